// Round 14
// baseline (199.861 us; speedup 1.0000x reference)
//
#include <hip/hip_runtime.h>
#include <hip/hip_bf16.h>
#include <math.h>

typedef __attribute__((ext_vector_type(8))) short short8;
typedef __attribute__((ext_vector_type(4))) short short4v;
typedef __attribute__((ext_vector_type(4))) float f32x4;
typedef unsigned short ushort_t;

#define B_  4
#define T_  4096
#define C_  1024
#define HS_ 128

// scale folded into q at GEMM epilogue: C^-0.5 * log2(e) -> scores in log2 units
#define QSCALE 0.04508422002778011f

// R13: per-tile segment counts, sum = 256 per batch -> grid 1024 = 4
// blocks/CU (was 192 -> 768 = 3/CU).  Workspace headroom confirmed: the
// 256 MiB fillBufferAligned poisons ARE d_ws, so Opart can grow to 1024
// slots (33.6 MB).
__device__ const unsigned char NS_[32] = {
    1,1,1,2,2,3,3,4,4,5,5,6,6,7,7,8,8,9,9,10,10,11,11,12,12,13,13,14,14,15,15,15};

__device__ __forceinline__ ushort_t f2bf(float f) {      // RNE
    unsigned int u = __float_as_uint(f);
    u = (u + 0x7FFFu + ((u >> 16) & 1u)) >> 16;
    return (ushort_t)u;
}
__device__ __forceinline__ ushort_t f2bf_fast(float f) { // positive, ~RNE
    return (ushort_t)((__float_as_uint(f) + 0x8000u) >> 16);
}
__device__ __forceinline__ float bf2f(ushort_t u) {
    return __uint_as_float(((unsigned)u) << 16);
}
__device__ __forceinline__ void async16(const void* g, void* l) {
    __builtin_amdgcn_global_load_lds(
        (const __attribute__((address_space(1))) unsigned int*)g,
        (__attribute__((address_space(3))) unsigned int*)l, 16, 0, 0);
}
__device__ __forceinline__ float exp2fast(float x) {
    return __builtin_amdgcn_exp2f(x);
}
__device__ __forceinline__ void stnt8(ushort_t* p, short8 v) {
    __builtin_nontemporal_store(v, (short8*)p);
}

// ---------------------------------------------------------------------------
// Kernel 1: W [1024][128] fp32 -> WT bf16 [m][h][k] via LDS transpose.
// ---------------------------------------------------------------------------
__global__ __launch_bounds__(256) void wt_kernel(
    const float* __restrict__ Wq, const float* __restrict__ Wk,
    const float* __restrict__ Wv, ushort_t* __restrict__ WT3)
{
    __shared__ ushort_t sWT[128 * 68];
    const int blk = blockIdx.x, tid = threadIdx.x;
    const int m = blk >> 4, slab = blk & 15;
    const float* __restrict__ W = (m == 0) ? Wq : (m == 1) ? Wk : Wv;
    const int kc = slab * 64;
    const int r = tid >> 2, h0 = (tid & 3) * 32;
#pragma unroll
    for (int j = 0; j < 8; ++j) {
        float4 wv = *(const float4*)(W + (size_t)(kc + r) * 128 + h0 + j * 4);
        sWT[(h0 + j * 4 + 0) * 68 + r] = f2bf(wv.x);
        sWT[(h0 + j * 4 + 1) * 68 + r] = f2bf(wv.y);
        sWT[(h0 + j * 4 + 2) * 68 + r] = f2bf(wv.z);
        sWT[(h0 + j * 4 + 3) * 68 + r] = f2bf(wv.w);
    }
    __syncthreads();
#pragma unroll
    for (int j = 0; j < 4; ++j) {
        int d = j * 256 + tid;
        int h = d >> 3, c8 = d & 7;
        short8 o;
#pragma unroll
        for (int e = 0; e < 8; ++e) o[e] = (short)sWT[h * 68 + c8 * 8 + e];
        *(short8*)(WT3 + (size_t)(m * 128 + h) * 1024 + kc + c8 * 8) = o;
    }
}

// ---------------------------------------------------------------------------
// Kernel 2: qkv = x @ W.  64x128 tile, BK=64, double-buffered, (256,3) grid.
// R11 wave repartition (64x32 per wave): 12 b128 LDS reads/iter/wave.
// ---------------------------------------------------------------------------
__global__ __launch_bounds__(256, 3) void qkv_gemm(
    const float* __restrict__ x, const ushort_t* __restrict__ WT3,
    ushort_t* __restrict__ q, ushort_t* __restrict__ k,
    ushort_t* __restrict__ vT)
{
    __shared__ ushort_t smem[24576];      // [2] x (A 4096 | B 8192 shorts)

    const int tid  = threadIdx.x;
    const int t0   = blockIdx.x * 64;
    const int mm   = blockIdx.y;
    const int w    = tid >> 6, lane = tid & 63;
    const int quad = lane >> 4, l15 = lane & 15;

    const ushort_t* __restrict__ WTm = WT3 + (size_t)mm * (128 * 1024);

    const int arow = tid >> 3, ac = tid & 7;
    const float* __restrict__ gx = x + (size_t)(t0 + arow) * C_ + ac * 8;
    const int aswz = ((ac ^ (arow & 7)) * 8);

    const ushort_t* gB[4];
    int bdst[4];
#pragma unroll
    for (int j = 0; j < 4; ++j) {
        int d = j * 256 + tid, row = d >> 3, c = d & 7;
        gB[j] = WTm + (size_t)row * C_ + ((c ^ (row & 7)) * 8);
        bdst[j] = 4096 + d * 8;
    }

    f32x4 acc[4][2];
#pragma unroll
    for (int mt = 0; mt < 4; ++mt)
#pragma unroll
        for (int nt = 0; nt < 2; ++nt) acc[mt][nt] = (f32x4)0.f;

    float4 ar[2][2];
#pragma unroll
    for (int p = 0; p < 2; ++p) {
        ar[p][0] = *(const float4*)(gx + (size_t)(p * 32) * C_);
        ar[p][1] = *(const float4*)(gx + (size_t)(p * 32) * C_ + 4);
    }
#pragma unroll
    for (int j = 0; j < 4; ++j) async16(gB[j], &smem[bdst[j]]);
#pragma unroll
    for (int p = 0; p < 2; ++p) {
        short8 sv;
        sv[0]=f2bf(ar[p][0].x); sv[1]=f2bf(ar[p][0].y);
        sv[2]=f2bf(ar[p][0].z); sv[3]=f2bf(ar[p][0].w);
        sv[4]=f2bf(ar[p][1].x); sv[5]=f2bf(ar[p][1].y);
        sv[6]=f2bf(ar[p][1].z); sv[7]=f2bf(ar[p][1].w);
        *(short8*)&smem[(p * 32 + arow) * 64 + aswz] = sv;
    }
    __syncthreads();

    for (int it = 0; it < 16; ++it) {
        const int buf = it & 1, nb = buf ^ 1;
        const bool more = (it < 15);
        if (more) {
            const int kc = (it + 1) * 64;
#pragma unroll
            for (int p = 0; p < 2; ++p) {
                ar[p][0] = *(const float4*)(gx + (size_t)(p * 32) * C_ + kc);
                ar[p][1] = *(const float4*)(gx + (size_t)(p * 32) * C_ + kc + 4);
            }
#pragma unroll
            for (int j = 0; j < 4; ++j)
                async16(gB[j] + kc, &smem[nb * 12288 + bdst[j]]);
        }
        const ushort_t* sA = &smem[buf * 12288];
        const ushort_t* sB = &smem[buf * 12288 + 4096];
#pragma unroll
        for (int kf = 0; kf < 2; ++kf) {
            const int kc8 = kf * 4 + quad;
            short8 af[4], bfr[2];
#pragma unroll
            for (int mt = 0; mt < 4; ++mt) {
                int r = mt * 16 + l15;
                af[mt] = *(const short8*)&sA[r * 64 + ((kc8 ^ (r & 7)) * 8)];
            }
#pragma unroll
            for (int nt = 0; nt < 2; ++nt) {
                int r = w * 32 + nt * 16 + l15;
                bfr[nt] = *(const short8*)&sB[r * 64 + ((kc8 ^ (r & 7)) * 8)];
            }
#pragma unroll
            for (int mt = 0; mt < 4; ++mt)
#pragma unroll
                for (int nt = 0; nt < 2; ++nt)
                    acc[mt][nt] = __builtin_amdgcn_mfma_f32_16x16x32_bf16(
                        af[mt], bfr[nt], acc[mt][nt], 0, 0, 0);
        }
        if (more) {
#pragma unroll
            for (int p = 0; p < 2; ++p) {
                short8 sv;
                sv[0]=f2bf(ar[p][0].x); sv[1]=f2bf(ar[p][0].y);
                sv[2]=f2bf(ar[p][0].z); sv[3]=f2bf(ar[p][0].w);
                sv[4]=f2bf(ar[p][1].x); sv[5]=f2bf(ar[p][1].y);
                sv[6]=f2bf(ar[p][1].z); sv[7]=f2bf(ar[p][1].w);
                *(short8*)&smem[nb * 12288 + (p * 32 + arow) * 64 + aswz] = sv;
            }
        }
        __syncthreads();
    }

    if (mm < 2) {
        ushort_t* __restrict__ outp = (mm == 0) ? q : k;
        const float s = (mm == 0) ? QSCALE : 1.0f;
        ushort_t* sE = &smem[0];            // 64 x 136
#pragma unroll
        for (int mt = 0; mt < 4; ++mt)
#pragma unroll
            for (int nt = 0; nt < 2; ++nt)
#pragma unroll
                for (int rr = 0; rr < 4; ++rr)
                    sE[(mt * 16 + quad * 4 + rr) * 136 + w * 32 + nt * 16 + l15] =
                        f2bf(acc[mt][nt][rr] * s);
        __syncthreads();
#pragma unroll
        for (int j = 0; j < 4; ++j) {
            int d = j * 256 + tid;
            int row = d >> 4, cs = d & 15;
            *(short8*)(outp + (size_t)(t0 + row) * HS_ + cs * 8) =
                *(const short8*)&sE[row * 136 + cs * 8];
        }
    } else {
        ushort_t* sT = &smem[0];            // 64 x 132
#pragma unroll
        for (int mt = 0; mt < 4; ++mt)
#pragma unroll
            for (int nt = 0; nt < 2; ++nt)
#pragma unroll
                for (int rr = 0; rr < 4; ++rr)
                    sT[(mt * 16 + quad * 4 + rr) * 132 + w * 32 + nt * 16 + l15] =
                        f2bf(acc[mt][nt][rr]);
        __syncthreads();
        const int bb = t0 >> 12;
        const int tl = t0 & (T_ - 1);
#pragma unroll
        for (int j = 0; j < 4; ++j) {
            int d = j * 256 + tid;
            int h = d >> 3, t8 = d & 7;
            short8 o;
#pragma unroll
            for (int e = 0; e < 8; ++e)
                o[e] = (short)sT[(t8 * 8 + e) * 132 + h];
            *(short8*)(vT + ((size_t)(bb * HS_) + h) * T_ + tl + t8 * 8) = o;
        }
    }
}

// ---------------------------------------------------------------------------
// Kernel 3: causal flash attention.  R7 sync; R9 vf-read-once; R10 V async16;
// R12 swapped QK^T + packed b64 P-spill.
// R13: 4 BLOCKS/CU.  (a) sP stride 40 -> 32 with sub-swizzle sigma = row&6
// (8-byte sub-chunks; sigma even keeps b64-write/b128-read adjacency and
// 16B alignment; both sides 2-way bank = free) -> LDS = 40960 B exactly
// (160KB/4).  (b) 256 segments/batch (NS_ sums 256) -> grid 1024 = 4/CU,
// +33% waves/SIMD to fill the serial per-chunk chain.  Workspace: Opart
// 1024 slots = 33.6 MB (d_ws = 256 MiB, per the harness poison fills).
// ---------------------------------------------------------------------------
__global__ __launch_bounds__(256, 4) void attn_seg(
    const ushort_t* __restrict__ q, const ushort_t* __restrict__ k,
    const ushort_t* __restrict__ vT, ushort_t* __restrict__ Opart,
    float* __restrict__ lseg)
{
    __shared__ ushort_t smem[20480];       // 40960 B -> 4 blocks/CU
    ushort_t* sKb = smem;                  // [2][4096] : 32 keys x 128 h, swz
    ushort_t* sVb = smem + 8192;           // [2][4096] : 128 h x 32, swz
    ushort_t* sP  = smem + 16384;          // [4][1024] : 32 q-rows x 32 kv, swz

    const int tid  = threadIdx.x;
    const int bid  = blockIdx.x;
    const int bb   = (bid & 7) >> 1;                  // XCD batch affinity
    const int seg  = ((bid >> 3) << 1) | (bid & 1);   // 0..255 within batch
    const int slot = bb * 256 + seg;
    int r_ = seg;
    int i = 0;
    while (r_ >= NS_[i]) { r_ -= NS_[i]; ++i; }
    const int s    = r_;
    const int ns   = NS_[i];
    const int qb   = i << 7;
    const int nkc  = (i + 1) << 2;           // 32-key chunks in causal range
    const int c0   = (nkc * s) / ns;
    const int c1   = (nkc * (s + 1)) / ns;

    const int w    = tid >> 6, lane = tid & 63;
    const int quad = lane >> 4, l15 = lane & 15;
    const int sig  = l15 & 6;                // sP sub-swizzle (row&6)
    const size_t bT = (size_t)bb << 12;

    // staging descriptors (K and V both async16, pre-swizzled global src)
    const int kr0 = tid >> 4,          kc0 = tid & 15;
    const int kr1 = (tid + 256) >> 4,  kc1 = (tid + 256) & 15;
    const ushort_t* kp0 = k + (bT + (size_t)c0 * 32 + kr0) * HS_ + ((kc0 ^ (kr0 & 15)) * 8);
    const ushort_t* kp1 = k + (bT + (size_t)c0 * 32 + kr1) * HS_ + ((kc1 ^ (kr1 & 15)) * 8);
    const int vr0 = tid >> 2,          vc0 = tid & 3;
    const int vr1 = (tid + 256) >> 2,  vc1 = (tid + 256) & 3;
    const int vs0 = (vc0 ^ ((vr0 ^ (vr0 >> 2)) & 3));
    const int vs1 = (vc1 ^ ((vr1 ^ (vr1 >> 2)) & 3));
    const ushort_t* vp0 = vT + ((size_t)(bb * HS_) + vr0) * T_ + c0 * 32 + vs0 * 8;
    const ushort_t* vp1 = vT + ((size_t)(bb * HS_) + vr1) * T_ + c0 * 32 + vs1 * 8;

    // Q fragments (A-layout straight from global; B-operand in swapped QK^T)
    short8 qf[2][4];
#pragma unroll
    for (int mt = 0; mt < 2; ++mt)
#pragma unroll
        for (int kf = 0; kf < 4; ++kf)
            qf[mt][kf] = *(const short8*)(
                q + (bT + qb + w * 32 + mt * 16 + l15) * HS_ + kf * 32 + quad * 8);

    f32x4 O[2][8];
    f32x4 O_l[2];
#pragma unroll
    for (int mt = 0; mt < 2; ++mt) {
        O_l[mt] = (f32x4)0.f;
#pragma unroll
        for (int nt = 0; nt < 8; ++nt) O[mt][nt] = (f32x4)0.f;
    }
    short8 ones;
#pragma unroll
    for (int e = 0; e < 8; ++e) ones[e] = (short)0x3F80;

    // prologue: stage chunk c0 into buf 0 (K and V via async16)
    {
        async16(kp0, sKb + tid * 8);
        async16(kp1, sKb + (tid + 256) * 8);
        async16(vp0, sVb + tid * 8);
        async16(vp1, sVb + (tid + 256) * 8);
        kp0 += 32 * HS_; kp1 += 32 * HS_; vp0 += 32; vp1 += 32;
    }
    __syncthreads();

    for (int c = c0; c < c1; ++c) {
        const int buf = (c - c0) & 1, nb = buf ^ 1;
        const int kb = c << 5;
        const bool more = (c + 1 < c1);
        if (more) {                          // prefetch chunk c+1 (async)
            async16(kp0, sKb + nb * 4096 + tid * 8);
            async16(kp1, sKb + nb * 4096 + (tid + 256) * 8);
            async16(vp0, sVb + nb * 4096 + tid * 8);
            async16(vp1, sVb + nb * 4096 + (tid + 256) * 8);
            kp0 += 32 * HS_; kp1 += 32 * HS_; vp0 += 32; vp1 += 32;
        }
        const ushort_t* sK = sKb + buf * 4096;
        const ushort_t* sV = sVb + buf * 4096;

        // ---- QK^T swapped: lane holds P[q=mt*16+l15][kv=nt*16+quad*4+rr]
        f32x4 S[2][2];
        S[0][0] = (f32x4)0.f; S[0][1] = (f32x4)0.f;
        S[1][0] = (f32x4)0.f; S[1][1] = (f32x4)0.f;
#pragma unroll
        for (int nt = 0; nt < 2; ++nt) {
            int row = nt * 16 + l15;
#pragma unroll
            for (int kf = 0; kf < 4; ++kf) {
                short8 kfr = *(const short8*)&sK[row * 128 + (((kf * 4 + quad) ^ l15) * 8)];
                S[0][nt] = __builtin_amdgcn_mfma_f32_16x16x32_bf16(kfr, qf[0][kf], S[0][nt], 0, 0, 0);
                S[1][nt] = __builtin_amdgcn_mfma_f32_16x16x32_bf16(kfr, qf[1][kf], S[1][nt], 0, 0, 0);
            }
        }
        // ---- causal mask (diagonal chunks only; swapped indices) ----
        if (kb + 31 > qb + w * 32) {
#pragma unroll
            for (int mt = 0; mt < 2; ++mt)
#pragma unroll
                for (int nt = 0; nt < 2; ++nt)
#pragma unroll
                    for (int rr = 0; rr < 4; ++rr)
                        if (kb + nt * 16 + quad * 4 + rr > qb + w * 32 + mt * 16 + l15)
                            S[mt][nt][rr] = -1e30f;
        }
        // ---- softmax: p = exp2(S); packed b64 spill, swizzled stride-32 ----
#pragma unroll
        for (int mt = 0; mt < 2; ++mt)
#pragma unroll
            for (int nt = 0; nt < 2; ++nt) {
                short4v pv;
#pragma unroll
                for (int rr = 0; rr < 4; ++rr)
                    pv[rr] = (short)f2bf_fast(exp2fast(S[mt][nt][rr]));
                *(short4v*)&sP[w * 1024 + (mt * 16 + l15) * 32 +
                               ((nt * 4 + quad) ^ sig) * 4] = pv;
            }
        // ---- PV + row-sums via ones-MFMA (vf read once, shared mt) ----
        {
            short8 pf0 = *(short8*)&sP[w * 1024 + (l15) * 32 + ((2 * quad) ^ sig) * 4];
            short8 pf1 = *(short8*)&sP[w * 1024 + (16 + l15) * 32 + ((2 * quad) ^ sig) * 4];
            O_l[0] = __builtin_amdgcn_mfma_f32_16x16x32_bf16(pf0, ones, O_l[0], 0, 0, 0);
            O_l[1] = __builtin_amdgcn_mfma_f32_16x16x32_bf16(pf1, ones, O_l[1], 0, 0, 0);
#pragma unroll
            for (int nt = 0; nt < 8; ++nt) {
                int row = nt * 16 + l15;
                int cch = quad ^ ((row ^ (row >> 2)) & 3);
                short8 vf = *(const short8*)&sV[row * 32 + cch * 8];
                O[0][nt] = __builtin_amdgcn_mfma_f32_16x16x32_bf16(pf0, vf, O[0][nt], 0, 0, 0);
                O[1][nt] = __builtin_amdgcn_mfma_f32_16x16x32_bf16(pf1, vf, O[1][nt], 0, 0, 0);
            }
        }
        __syncthreads();                     // one barrier per chunk
    }

    // ---- epilogue: bf16 partials via LDS coalesce, l from ones-MFMA ----
    ushort_t* sE = smem;                     // 128 x 136 (17408 <= 20480)
#pragma unroll
    for (int mt = 0; mt < 2; ++mt)
#pragma unroll
        for (int nt = 0; nt < 8; ++nt)
#pragma unroll
            for (int rr = 0; rr < 4; ++rr)
                sE[(w * 32 + mt * 16 + quad * 4 + rr) * 136 + nt * 16 + l15] =
                    f2bf(O[mt][nt][rr]);
    if (l15 == 0)
#pragma unroll
        for (int mt = 0; mt < 2; ++mt)
#pragma unroll
            for (int rr = 0; rr < 4; ++rr)
                lseg[slot * 128 + w * 32 + mt * 16 + quad * 4 + rr] = O_l[mt][rr];
    __syncthreads();
#pragma unroll
    for (int j = 0; j < 8; ++j) {
        int d = j * 256 + tid;
        int row = d >> 4, cs = d & 15;
        stnt8(Opart + (size_t)slot * 16384 + row * 128 + cs * 8,
              *(const short8*)&sE[row * 136 + cs * 8]);
    }
}

// ---------------------------------------------------------------------------
// Kernel 4: combine: out = (sum_s O_s) / (sum_s l_s).  grid = 1024.
// ---------------------------------------------------------------------------
__global__ __launch_bounds__(256) void combine_kernel(
    const ushort_t* __restrict__ Opart, const float* __restrict__ lseg,
    float* __restrict__ out)
{
    const int blk  = blockIdx.x;           // 1024
    const int tile = blk >> 3, rg = blk & 7;
    const int i    = tile & 31;
    int sb = (tile >> 5) * 256;
    for (int j = 0; j < i; ++j) sb += NS_[j];
    const int ns  = NS_[i];
    const int row = rg * 16 + (threadIdx.x >> 4);
    const int col = (threadIdx.x & 15) * 8;

    const ushort_t* op = Opart + (size_t)sb * 16384 + row * 128 + col;
    const float*    lp = lseg + sb * 128 + row;

    float den = lp[0];
    short8 cur = *(const short8*)op;
    float acc[8];
#pragma unroll
    for (int e = 0; e < 8; ++e) acc[e] = 0.f;
    for (int s = 1; s < ns; ++s) {
        short8 nxt = *(const short8*)(op + (size_t)s * 16384);
        float  dn  = lp[s * 128];
#pragma unroll
        for (int e = 0; e < 8; ++e) acc[e] += bf2f((ushort_t)cur[e]);
        den += dn;
        cur = nxt;
    }
#pragma unroll
    for (int e = 0; e < 8; ++e) acc[e] += bf2f((ushort_t)cur[e]);

    const float inv = 1.0f / den;
    float* o = out + ((size_t)tile * 128 + row) * 128 + col;
    float4 v0 = make_float4(acc[0] * inv, acc[1] * inv, acc[2] * inv, acc[3] * inv);
    float4 v1 = make_float4(acc[4] * inv, acc[5] * inv, acc[6] * inv, acc[7] * inv);
    *(float4*)o = v0;
    *(float4*)(o + 4) = v1;
}

// ---------------------------------------------------------------------------
extern "C" void kernel_launch(void* const* d_in, const int* in_sizes, int n_in,
                              void* d_out, int out_size, void* d_ws, size_t ws_size,
                              hipStream_t stream)
{
    const float* x  = (const float*)d_in[0];
    const float* Wq = (const float*)d_in[1];
    const float* Wk = (const float*)d_in[2];
    const float* Wv = (const float*)d_in[3];
    float* out = (float*)d_out;

    ushort_t* WT3 = (ushort_t*)d_ws;               // 393,216 shorts
    ushort_t* q   = WT3 + 393216;                  // 2,097,152
    ushort_t* k   = q + 2097152;
    ushort_t* vT  = k + 2097152;                   // [B][HS][T]
    ushort_t* Opart = vT + 2097152;                // 1024 slots x 16384 bf16 (33.6 MB)
    float* lseg   = (float*)(Opart + 1024 * 16384);

    wt_kernel<<<48, 256, 0, stream>>>(Wq, Wk, Wv, WT3);
    qkv_gemm<<<dim3(256, 3), 256, 0, stream>>>(x, WT3, q, k, vT);
    attn_seg<<<1024, 256, 0, stream>>>(q, k, vT, Opart, lseg);
    combine_kernel<<<1024, 256, 0, stream>>>(Opart, lseg, out);
}